// Round 10
// baseline (597.332 us; speedup 1.0000x reference)
//
#include <hip/hip_runtime.h>
#include <stdint.h>

#define NN 8192
#define DD 512
#define EE 131072
#define BBATCH 16
#define NPG 512
#define SSEL 128
#define LL 3

typedef unsigned short u16;
typedef unsigned char u8;
typedef __bf16 bf16x8 __attribute__((ext_vector_type(8)));
typedef float f32x4 __attribute__((ext_vector_type(4)));
typedef float f32x2 __attribute__((ext_vector_type(2)));
typedef u16 u16x8 __attribute__((ext_vector_type(8)));

__device__ __forceinline__ float bf2f(u16 u) {
    union { unsigned i; float f; } v; v.i = ((unsigned)u) << 16; return v.f;
}
__device__ __forceinline__ u16 f2bf(float f) {
    union { unsigned i; float f; } v; v.f = f;
    unsigned i = v.i;
    return (u16)((i + 0x7FFFu + ((i >> 16) & 1u)) >> 16);  // RNE
}

// pack two fp32 -> packed bf16x2 in one uint (lo = s0, hi = s1)
__device__ __forceinline__ unsigned pk_bf16(float s0, float s1) {
#if __has_builtin(__builtin_amdgcn_cvt_pk_bf16_f32)
    typedef __bf16 bf16x2 __attribute__((ext_vector_type(2)));
    union { bf16x2 v; unsigned u; } r;
    r.v = __builtin_amdgcn_cvt_pk_bf16_f32(s0, s1);
    return r.u;
#else
    unsigned r0 = __float_as_uint(s0);
    r0 = (r0 + 0x7FFFu + ((r0 >> 16) & 1u)) >> 16;
    unsigned r1 = __float_as_uint(s1);
    r1 = (r1 + 0x7FFFu + ((r1 >> 16) & 1u)) & 0xffff0000u;
    return r0 | r1;
#endif
}

// fp8 e4m3 <-> f32 (HW cvt on gfx950; SW fallback)
__device__ __forceinline__ u8 f32_fp8(float f) {
#if __has_builtin(__builtin_amdgcn_cvt_pk_fp8_f32)
    return (u8)((unsigned)__builtin_amdgcn_cvt_pk_fp8_f32(f, f, 0, false) & 0xffu);
#else
    unsigned u = __float_as_uint(f);
    int s = (u >> 31) & 1;
    int exp = (int)((u >> 23) & 255) - 127;
    unsigned man = (u >> 20) & 7;
    if (exp < -6) return (u8)(s << 7);
    if (exp > 8) { exp = 8; man = 7; }
    return (u8)((s << 7) | ((exp + 7) << 3) | man);
#endif
}
// SEL is a template param: the builtin requires an immediate operand.
template <int SEL>
__device__ __forceinline__ f32x2 fp8pair_f32(unsigned w) {
#if __has_builtin(__builtin_amdgcn_cvt_pk_f32_fp8)
    f32x2 r;
    r = __builtin_amdgcn_cvt_pk_f32_fp8(w, SEL);
    return r;
#else
    f32x2 r;
    #pragma unroll
    for (int i = 0; i < 2; ++i) {
        unsigned u = (w >> (SEL * 16 + i * 8)) & 0xffu;
        unsigned s = (u >> 7) & 1, e = (u >> 3) & 15, m = u & 7;
        float v = (e == 0) ? (float)m * 0.001953125f
                           : (float)(8 + m) * exp2f((float)e - 10.f);
        r[i] = s ? -v : v;
    }
    return r;
#endif
}

// async global->LDS, 16B per lane, LDS dest = wave-uniform base + lane*16
__device__ __forceinline__ void async_cp16(const u16* g, u16* l) {
    __builtin_amdgcn_global_load_lds(
        (const __attribute__((address_space(1))) unsigned int*)g,
        (__attribute__((address_space(3))) unsigned int*)l, 16, 0, 0);
}

// ---------------- LayerNorm (+ optional residual-add + agg zeroing)
// 4 rows per 256-thr block (wave per row)
__global__ __launch_bounds__(256) void ln_fused(const float* __restrict__ xin,
                                                float* __restrict__ agg_io,
                                                float* __restrict__ xout,
                                                const float* __restrict__ g,
                                                const float* __restrict__ b,
                                                u16* __restrict__ h, int doAdd) {
    int row = blockIdx.x * 4 + (threadIdx.x >> 6);
    int lane = threadIdx.x & 63;
    const f32x4* x4 = (const f32x4*)(xin + (size_t)row * DD);
    f32x4 p = x4[lane * 2], q = x4[lane * 2 + 1];
    if (doAdd) {
        const f32x4* a4 = (const f32x4*)(agg_io + (size_t)row * DD);
        f32x4 pa = a4[lane * 2], qa = a4[lane * 2 + 1];
        #pragma unroll
        for (int i = 0; i < 4; ++i) { p[i] += pa[i]; q[i] += qa[i]; }
    }
    if (agg_io) {
        f32x4 z;
        #pragma unroll
        for (int i = 0; i < 4; ++i) z[i] = 0.f;
        f32x4* a4 = (f32x4*)(agg_io + (size_t)row * DD);
        a4[lane * 2] = z;
        a4[lane * 2 + 1] = z;
    }
    f32x4* xo = (f32x4*)(xout + (size_t)row * DD);
    xo[lane * 2] = p;
    xo[lane * 2 + 1] = q;
    float v[8];
    v[0] = p[0]; v[1] = p[1]; v[2] = p[2]; v[3] = p[3];
    v[4] = q[0]; v[5] = q[1]; v[6] = q[2]; v[7] = q[3];
    float s = 0.f, sq = 0.f;
    #pragma unroll
    for (int i = 0; i < 8; ++i) { s += v[i]; sq += v[i] * v[i]; }
    #pragma unroll
    for (int o = 32; o >= 1; o >>= 1) { s += __shfl_xor(s, o); sq += __shfl_xor(sq, o); }
    float mu = s * (1.f / DD);
    float var = sq * (1.f / DD) - mu * mu;
    float rs = rsqrtf(var + 1e-5f);
    int kb = lane * 8;
    u16x8 o8;
    #pragma unroll
    for (int i = 0; i < 8; ++i) o8[i] = f2bf((v[i] - mu) * rs * g[kb + i] + b[kb + i]);
    *(u16x8*)(h + (size_t)row * DD + kb) = o8;
}

// ---------------- counting sort by dst
__global__ void hist_kernel(const int* __restrict__ dst, int* __restrict__ cnt) {
    int e = blockIdx.x * 256 + threadIdx.x;
    if (e < EE) atomicAdd(&cnt[dst[e]], 1);
}

__global__ __launch_bounds__(1024) void scan_kernel(const int* __restrict__ cnt,
                                                    int* __restrict__ off,
                                                    int* __restrict__ cur) {
    __shared__ int part[1024];
    int t = threadIdx.x;
    int base = t * 8;
    int loc[8]; int s = 0;
    #pragma unroll
    for (int i = 0; i < 8; ++i) { loc[i] = s; s += cnt[base + i]; }
    part[t] = s;
    __syncthreads();
    for (int o = 1; o < 1024; o <<= 1) {
        int v = part[t];
        int u = (t >= o) ? part[t - o] : 0;
        __syncthreads();
        part[t] = v + u;
        __syncthreads();
    }
    int bx = (t > 0) ? part[t - 1] : 0;
    #pragma unroll
    for (int i = 0; i < 8; ++i) { off[base + i] = bx + loc[i]; cur[base + i] = bx + loc[i]; }
    if (t == 0) off[NN] = part[1023];
}

__global__ void scatter_kernel(const int* __restrict__ src, const int* __restrict__ dst,
                               int* __restrict__ cur, int* __restrict__ ssrc,
                               int* __restrict__ sdst) {
    int e = blockIdx.x * 256 + threadIdx.x;
    if (e < EE) {
        int d = dst[e];
        int p = atomicAdd(&cur[d], 1);
        ssrc[p] = src[e];
        sdst[p] = d;
    }
}

// ---------------- 5x fused cvt+transpose for 512x512 fp32 mats -> bf16 [N][K]
struct CvtJobs {
    const float* s[5];
    u16* d[5];
};
__global__ __launch_bounds__(256) void cvt_t5_kernel(CvtJobs jobs) {
    __shared__ u16 tile[32][33];
    const float* src = jobs.s[blockIdx.z];
    u16* dstp = jobs.d[blockIdx.z];
    int bk = blockIdx.x * 32, bn = blockIdx.y * 32;
    int tx = threadIdx.x & 31, ty = threadIdx.x >> 5;  // 32 x 8
    #pragma unroll
    for (int r = 0; r < 32; r += 8)
        tile[ty + r][tx] = f2bf(src[(size_t)(bk + ty + r) * 512 + bn + tx]);
    __syncthreads();
    #pragma unroll
    for (int r = 0; r < 32; r += 8)
        dstp[(size_t)(bn + ty + r) * 512 + bk + tx] = tile[tx][ty + r];
}

// W1 fp32 [L][1024][512] -> Wcat^T bf16 [L][1024 rows][512]:
// rows 0..511 = (W1a - W1b)^T ; rows 512..1023 = W1b^T. z = layer.
__global__ __launch_bounds__(256) void cvt_w1_kernel(const float* __restrict__ W1g,
                                                     u16* __restrict__ dstg) {
    __shared__ u16 tile[32][33];
    const float* W1 = W1g + (size_t)blockIdx.z * 1024 * 512;
    u16* dstp = dstg + (size_t)blockIdx.z * 1024 * 512;
    int bk = blockIdx.x * 32, bn = blockIdx.y * 32;
    int tx = threadIdx.x & 31, ty = threadIdx.x >> 5;
    #pragma unroll
    for (int r = 0; r < 32; r += 8) {
        int k = bk + ty + r, n = bn + tx;
        float v = (n < 512) ? (W1[(size_t)k * 512 + n] - W1[(size_t)(k + 512) * 512 + n])
                            : W1[(size_t)(k + 512) * 512 + (n - 512)];
        tile[ty + r][tx] = f2bf(v);
    }
    __syncthreads();
    #pragma unroll
    for (int r = 0; r < 32; r += 8)
        dstp[(size_t)(bn + ty + r) * 512 + bk + tx] = tile[tx][ty + r];
}

// ---------------- async MFMA GEMM, 128x128 tile, 256 threads (2x2 waves)
// EMODE 0: relu(acc+bias)->bf16 ; 1: acc+bias+resid->fp32 ; 2: acc->bf16 ;
// EMODE 3: P-GEMM split output: col<512 -> bf16 Pa (acc+b1), col>=512 -> fp8
//          Pb8 (acc only). Pb8 is 4MB -> per-XCD-L2-resident for gemm_edge.
template <int EMODE>
__global__ __launch_bounds__(256) void gemm_async(
    const u16* __restrict__ A, const u16* __restrict__ BT,
    const float* __restrict__ bias, const float* __restrict__ resid,
    void* __restrict__ Cout, u8* __restrict__ CoutB, int K, int ldc) {
    __shared__ u16 lA[128 * 64];
    __shared__ u16 lB[128 * 64];
    const int tid = threadIdx.x;
    const int lane = tid & 63, wave = tid >> 6;
    const int wm = wave & 1, wn = wave >> 1;
    const int quad = lane >> 4, lm = lane & 15;
    const int tileM = blockIdx.x, tileN = blockIdx.y;

    const int g = (lane & 7) ^ (lane >> 3);
    const u16* ap[4];
    const u16* bp[4];
    u16* lad[4];
    u16* lbd[4];
    #pragma unroll
    for (int j = 0; j < 4; ++j) {
        int seg = wave * 4 + j;
        int rA = tileM * 128 + seg * 8 + (lane >> 3);
        int rB = tileN * 128 + seg * 8 + (lane >> 3);
        ap[j] = A + (size_t)rA * K + g * 8;
        bp[j] = BT + (size_t)rB * K + g * 8;
        lad[j] = lA + seg * 512;
        lbd[j] = lB + seg * 512;
    }

    f32x4 acc[4][4];
    #pragma unroll
    for (int mt = 0; mt < 4; ++mt)
        #pragma unroll
        for (int nt = 0; nt < 4; ++nt)
            #pragma unroll
            for (int j = 0; j < 4; ++j) acc[mt][nt][j] = 0.f;

    for (int kb = 0; kb < K; kb += 64) {
        #pragma unroll
        for (int j = 0; j < 4; ++j) {
            async_cp16(ap[j], lad[j]);
            async_cp16(bp[j], lbd[j]);
            ap[j] += 64;
            bp[j] += 64;
        }
        __syncthreads();
        #pragma unroll
        for (int kk = 0; kk < 64; kk += 32) {
            bf16x8 af[4], bfr[4];
            int gbase = (kk >> 3) + quad;
            #pragma unroll
            for (int mt = 0; mt < 4; ++mt) {
                int row = wm * 64 + mt * 16 + lm;
                af[mt] = *(const bf16x8*)(lA + row * 64 + ((gbase ^ (row & 7)) << 3));
            }
            #pragma unroll
            for (int nt = 0; nt < 4; ++nt) {
                int row = wn * 64 + nt * 16 + lm;
                bfr[nt] = *(const bf16x8*)(lB + row * 64 + ((gbase ^ (row & 7)) << 3));
            }
            #pragma unroll
            for (int mt = 0; mt < 4; ++mt)
                #pragma unroll
                for (int nt = 0; nt < 4; ++nt)
                    acc[mt][nt] = __builtin_amdgcn_mfma_f32_16x16x32_bf16(
                        af[mt], bfr[nt], acc[mt][nt], 0, 0, 0);
        }
        __syncthreads();
    }
    #pragma unroll
    for (int mt = 0; mt < 4; ++mt) {
        #pragma unroll
        for (int nt = 0; nt < 4; ++nt) {
            int col = tileN * 128 + wn * 64 + nt * 16 + lm;
            float bv;
            if (EMODE == 2) bv = 0.f;
            else if (EMODE == 3) bv = (col < 512) ? bias[col] : 0.f;
            else bv = bias[col];
            #pragma unroll
            for (int j = 0; j < 4; ++j) {
                int grow = tileM * 128 + wm * 64 + mt * 16 + quad * 4 + j;
                float v = acc[mt][nt][j] + bv;
                if (EMODE == 0) {
                    ((u16*)Cout)[(size_t)grow * ldc + col] = f2bf(fmaxf(v, 0.f));
                } else if (EMODE == 1) {
                    ((float*)Cout)[(size_t)grow * ldc + col] =
                        v + resid[(size_t)grow * ldc + col];
                } else if (EMODE == 3) {
                    if (col < 512)
                        ((u16*)Cout)[(size_t)grow * 512 + col] = f2bf(v);
                    else
                        CoutB[(size_t)grow * 512 + (col - 512)] = f32_fp8(v);
                } else {
                    ((u16*)Cout)[(size_t)grow * ldc + col] = f2bf(v);
                }
            }
        }
    }
}

// ---------------- fused edge GEMM, tile 64 edges x 256 cols, 256 thr (4 waves,
// wave-tile 64x64 each: wave wn covers all 64 edge rows x cols wn*64..+64).
// LDS 41KB -> 3 blocks/CU; __launch_bounds__(256,3) allows regs for a register
// prefetch of next-iter gathers WITHOUT the round-5 occupancy penalty.
// Per iter: issue 8 B global_load_lds, then 4 next-iter gathers (kept in
// flight across the barrier via s_waitcnt vmcnt(4)); combine reads registers
// loaded one iter earlier -> no global latency in the serial path.
__global__ __launch_bounds__(256, 3) void gemm_edge(
    const u16* __restrict__ Pa, const u8* __restrict__ Pb8,
    const int* __restrict__ ssrc, const int* __restrict__ sdst,
    const u16* __restrict__ W2T, const float* __restrict__ b2,
    float* __restrict__ agg) {
    __shared__ u16 smem[64 * 64 + 256 * 64];  // lA 8KB + lB 32KB
    __shared__ int nid_l[64];
    u16* lA = smem;
    u16* lB = smem + 64 * 64;
    const int bid = blockIdx.x;
    const int tileN = bid & 1;            // col half
    const int ebase = (bid >> 1) * 64;    // 64-edge tile
    const int tid = threadIdx.x;
    const int lane = tid & 63, wave = tid >> 6;  // 4 waves
    const int wn = wave;                          // wave tile 64(M) x 64(N)
    const int quad = lane >> 4, lm = lane & 15;

    if (tid < 64) nid_l[tid] = sdst[ebase + tid];

    const int g = (lane & 7) ^ (lane >> 3);
    // A staging: 2 segments of 8 rows each (64 rows / 4 waves = 16 rows/wave)
    int aoff[2], boff[2];
    u16* lout[2];
    #pragma unroll
    for (int j = 0; j < 2; ++j) {
        int seg = wave * 2 + j;              // 0..7
        int row = seg * 8 + (lane >> 3);
        int dn = sdst[ebase + row];
        int sn = ssrc[ebase + row];
        aoff[j] = dn * 512 + g * 8;   // bf16 elements
        boff[j] = sn * 512 + g * 8;   // fp8 bytes
        lout[j] = lA + seg * 512 + lane * 8;
    }
    // B async staging: 8 segments of 8 rows per wave (256 rows total)
    int woff[8];
    u16* lbd[8];
    #pragma unroll
    for (int j = 0; j < 8; ++j) {
        int seg = wave * 8 + j;  // 0..31
        int row = tileN * 256 + seg * 8 + (lane >> 3);
        woff[j] = row * 512 + g * 8;
        lbd[j] = lB + seg * 512;
    }

    f32x4 acc[4][4];
    #pragma unroll
    for (int mt = 0; mt < 4; ++mt)
        #pragma unroll
        for (int nt = 0; nt < 4; ++nt)
            #pragma unroll
            for (int j = 0; j < 4; ++j) acc[mt][nt][j] = 0.f;

    // preload gathers for iter 0
    u16x8 ga[2];
    uint2 gb[2];
    #pragma unroll
    for (int j = 0; j < 2; ++j) {
        ga[j] = *(const u16x8*)(Pa + aoff[j]);
        gb[j] = *(const uint2*)(Pb8 + boff[j]);
    }

    for (int kb = 0; kb < 512; kb += 64) {
        // B async copies first (drained at the manual barrier)...
        #pragma unroll
        for (int j = 0; j < 8; ++j) async_cp16(W2T + woff[j] + kb, lbd[j]);
        asm volatile("" ::: "memory");
        // ...then next-iter gathers (newest in vmcnt queue -> stay in flight)
        u16x8 gan[2];
        uint2 gbn[2];
        if (kb < 448) {
            #pragma unroll
            for (int j = 0; j < 2; ++j) {
                gan[j] = *(const u16x8*)(Pa + aoff[j] + kb + 64);
                gbn[j] = *(const uint2*)(Pb8 + boff[j] + kb + 64);
            }
        }
        asm volatile("" ::: "memory");
        // combine current-iter regs: t = relu(Pa' + Pb) -> lA
        #pragma unroll
        for (int j = 0; j < 2; ++j) {
            union { u16x8 v; unsigned w[4]; } ua;
            ua.v = ga[j];
            unsigned pw0 = gb[j].x, pw1 = gb[j].y;
            f32x2 c0 = fp8pair_f32<0>(pw0);
            f32x2 c1 = fp8pair_f32<1>(pw0);
            f32x2 c2 = fp8pair_f32<0>(pw1);
            f32x2 c3 = fp8pair_f32<1>(pw1);
            unsigned o[4];
            #pragma unroll
            for (int q = 0; q < 4; ++q) {
                f32x2 a, c;
                a[0] = __uint_as_float(ua.w[q] << 16);
                a[1] = __uint_as_float(ua.w[q] & 0xffff0000u);
                c = (q == 0) ? c0 : (q == 1) ? c1 : (q == 2) ? c2 : c3;
                f32x2 s = a + c;
                s[0] = fmaxf(s[0], 0.f);
                s[1] = fmaxf(s[1], 0.f);
                o[q] = pk_bf16(s[0], s[1]);
            }
            *(uint4*)lout[j] = make_uint4(o[0], o[1], o[2], o[3]);
        }
        // drain the 8 B-copies + combine ds_writes; leave 4 gathers in flight
        if (kb < 448)
            asm volatile("s_waitcnt vmcnt(4) lgkmcnt(0)\n\ts_barrier" ::: "memory");
        else
            asm volatile("s_waitcnt vmcnt(0) lgkmcnt(0)\n\ts_barrier" ::: "memory");
        #pragma unroll
        for (int kk = 0; kk < 64; kk += 32) {
            bf16x8 af[4], bfr[4];
            int gbase = (kk >> 3) + quad;
            #pragma unroll
            for (int mt = 0; mt < 4; ++mt) {
                int row = mt * 16 + lm;
                af[mt] = *(const bf16x8*)(lA + row * 64 + ((gbase ^ (row & 7)) << 3));
            }
            #pragma unroll
            for (int nt = 0; nt < 4; ++nt) {
                int row = wn * 64 + nt * 16 + lm;
                bfr[nt] = *(const bf16x8*)(lB + row * 64 + ((gbase ^ (row & 7)) << 3));
            }
            #pragma unroll
            for (int mt = 0; mt < 4; ++mt)
                #pragma unroll
                for (int nt = 0; nt < 4; ++nt)
                    acc[mt][nt] = __builtin_amdgcn_mfma_f32_16x16x32_bf16(
                        af[mt], bfr[nt], acc[mt][nt], 0, 0, 0);
        }
        asm volatile("s_barrier" ::: "memory");
        #pragma unroll
        for (int j = 0; j < 2; ++j) {
            ga[j] = gan[j];
            gb[j] = gbn[j];
        }
    }

    // epilogue: single 64-row pass; cbuf 64 x 264 (33.8KB, aliases lA/lB)
    u16* cbuf = smem;
    #pragma unroll
    for (int nt = 0; nt < 4; ++nt) {
        int lcol = wn * 64 + nt * 16 + lm;
        float bv = b2[tileN * 256 + lcol];
        #pragma unroll
        for (int mt = 0; mt < 4; ++mt) {
            #pragma unroll
            for (int j2 = 0; j2 < 4; ++j2) {
                int row = mt * 16 + quad * 4 + j2;
                cbuf[row * 264 + lcol] = f2bf(fmaxf(acc[mt][nt][j2] + bv, 0.f));
            }
        }
    }
    __syncthreads();
    {
        int lcol = tid;  // 256 threads -> 256 cols
        int gcol = tileN * 256 + lcol;
        int cur = nid_l[0];
        float run = bf2f(cbuf[lcol]);
        for (int r = 1; r < 64; ++r) {
            int nd = nid_l[r];
            float v = bf2f(cbuf[r * 264 + lcol]);
            if (nd != cur) {
                atomicMax((unsigned int*)&agg[(size_t)cur * DD + gcol],
                          __float_as_uint(run));
                cur = nd;
                run = v;
            } else {
                run = fmaxf(run, v);
            }
        }
        atomicMax((unsigned int*)&agg[(size_t)cur * DD + gcol], __float_as_uint(run));
    }
}

// ---------------- gather selected rows with residual add: xs[i] = x[r] + agg[r]
__global__ __launch_bounds__(128) void gather_fused(const float* __restrict__ x,
                                                    const float* __restrict__ agg,
                                                    const int* __restrict__ sel,
                                                    float* __restrict__ xs) {
    int i = blockIdx.x;
    int b = i >> 7;
    int r = b * NPG + sel[i];
    const f32x4* srcp = (const f32x4*)(x + (size_t)r * DD);
    const f32x4* aggp = (const f32x4*)(agg + (size_t)r * DD);
    f32x4 v = srcp[threadIdx.x];
    f32x4 a = aggp[threadIdx.x];
    #pragma unroll
    for (int j = 0; j < 4; ++j) v[j] += a[j];
    ((f32x4*)(xs + (size_t)i * DD))[threadIdx.x] = v;
}

extern "C" void kernel_launch(void* const* d_in, const int* in_sizes, int n_in,
                              void* d_out, int out_size, void* d_ws, size_t ws_size,
                              hipStream_t stream) {
    const float* x_in = (const float*)d_in[0];
    const int* ei = (const int*)d_in[1];
    const int* sel = (const int*)d_in[2];
    const float* W1 = (const float*)d_in[4];
    const float* b1 = (const float*)d_in[5];
    const float* W2 = (const float*)d_in[6];
    const float* b2 = (const float*)d_in[7];
    const float* g1 = (const float*)d_in[8];
    const float* be1 = (const float*)d_in[9];
    const float* g2 = (const float*)d_in[10];
    const float* be2 = (const float*)d_in[11];
    const float* fW1 = (const float*)d_in[12];
    const float* fb1 = (const float*)d_in[13];
    const float* fW2 = (const float*)d_in[14];
    const float* fb2 = (const float*)d_in[15];
    float* out = (float*)d_out;

    char* w = (char*)d_ws;
    size_t off = 0;
    auto alloc = [&](size_t bytes) -> char* {
        char* p = w + off;
        off += (bytes + 255) & ~(size_t)255;
        return p;
    };
    float* xbuf = (float*)alloc((size_t)NN * DD * 4);
    float* agg  = (float*)alloc((size_t)NN * DD * 4);
    u16* h      = (u16*)alloc((size_t)NN * DD * 2);
    u16* Pa     = (u16*)alloc((size_t)NN * DD * 2);
    u8* Pb8     = (u8*)alloc((size_t)NN * DD);
    u16* W1T    = (u16*)alloc((size_t)LL * 1024 * DD * 2);
    u16* W2T    = (u16*)alloc((size_t)LL * DD * DD * 2);
    u16* FW1T   = (u16*)alloc((size_t)DD * DD * 2);
    u16* FW2T   = (u16*)alloc((size_t)DD * DD * 2);
    int* cnt    = (int*)alloc((size_t)NN * 4);
    int* offs   = (int*)alloc((size_t)(NN + 1) * 4);
    int* cur    = (int*)alloc((size_t)NN * 4);
    int* ssrc   = (int*)alloc((size_t)EE * 4);
    int* sdst   = (int*)alloc((size_t)EE * 4);
    float* xs   = (float*)alloc((size_t)BBATCH * SSEL * DD * 4);
    u16* hs     = (u16*)alloc((size_t)BBATCH * SSEL * DD * 2);
    u16* uu     = (u16*)alloc((size_t)BBATCH * SSEL * DD * 2);

    const int* esrc = ei;       // edge_index[0] = x_j
    const int* edst = ei + EE;  // edge_index[1] = x_i / aggregation index

    (void)hipMemsetAsync(cnt, 0, (size_t)NN * 4, stream);
    hist_kernel<<<EE / 256, 256, 0, stream>>>(edst, cnt);
    scan_kernel<<<1, 1024, 0, stream>>>(cnt, offs, cur);
    scatter_kernel<<<EE / 256, 256, 0, stream>>>(esrc, edst, cur, ssrc, sdst);

    // all weight conversions in 2 launches
    cvt_w1_kernel<<<dim3(16, 32, LL), 256, 0, stream>>>(W1, W1T);
    {
        CvtJobs jobs;
        jobs.s[0] = W2;
        jobs.s[1] = W2 + (size_t)DD * DD;
        jobs.s[2] = W2 + (size_t)2 * DD * DD;
        jobs.s[3] = fW1;
        jobs.s[4] = fW2;
        jobs.d[0] = W2T;
        jobs.d[1] = W2T + (size_t)DD * DD;
        jobs.d[2] = W2T + (size_t)2 * DD * DD;
        jobs.d[3] = FW1T;
        jobs.d[4] = FW2T;
        cvt_t5_kernel<<<dim3(16, 16, 5), 256, 0, stream>>>(jobs);
    }

    for (int l = 0; l < LL; ++l) {
        // x_l = x_{l-1} + agg ; h = LN(x_l) ; agg <- 0 for this layer's atomics
        ln_fused<<<NN / 4, 256, 0, stream>>>(l == 0 ? x_in : xbuf, agg, xbuf, g1, be1,
                                             h, l > 0 ? 1 : 0);
        // Pa = h @ (W1a-W1b) + b1 (bf16) ; Pb8 = fp8(h @ W1b)  [8192 x 512 each]
        {
            dim3 grid(NN / 128, 1024 / 128);
            gemm_async<3><<<grid, 256, 0, stream>>>(
                h, W1T + (size_t)l * 1024 * DD, b1 + (size_t)l * DD, nullptr, Pa, Pb8,
                DD, 512);
        }
        // fused: edge-combine + GEMM2 + relu + segmax-atomics into agg
        gemm_edge<<<2 * (EE / 64), 256, 0, stream>>>(
            Pa, Pb8, ssrc, sdst, W2T + (size_t)l * DD * DD, b2 + (size_t)l * DD, agg);
    }

    gather_fused<<<BBATCH * SSEL, 128, 0, stream>>>(xbuf, agg, sel, xs);
    ln_fused<<<BBATCH * SSEL / 4, 256, 0, stream>>>(xs, nullptr, xs, g2, be2, hs, 0);
    dim3 gridf(BBATCH * SSEL / 128, DD / 128);
    gemm_async<0><<<gridf, 256, 0, stream>>>(hs, FW1T, fb1, nullptr, uu, nullptr, DD,
                                             DD);
    gemm_async<1><<<gridf, 256, 0, stream>>>(uu, FW2T, fb2, xs, out, nullptr, DD, DD);
}

// Round 11
// 584.983 us; speedup vs baseline: 1.0211x; 1.0211x over previous
//
#include <hip/hip_runtime.h>
#include <stdint.h>

#define NN 8192
#define DD 512
#define EE 131072
#define BBATCH 16
#define NPG 512
#define SSEL 128
#define LL 3
#define LSTR 36  // LDS row stride in u16 (72 B = 9 granules of 8 B; pad kills conflicts)

typedef unsigned short u16;
typedef unsigned char u8;
typedef __bf16 bf16x8 __attribute__((ext_vector_type(8)));
typedef float f32x4 __attribute__((ext_vector_type(4)));
typedef float f32x2 __attribute__((ext_vector_type(2)));
typedef u16 u16x8 __attribute__((ext_vector_type(8)));

__device__ __forceinline__ float bf2f(u16 u) {
    union { unsigned i; float f; } v; v.i = ((unsigned)u) << 16; return v.f;
}
__device__ __forceinline__ u16 f2bf(float f) {
    union { unsigned i; float f; } v; v.f = f;
    unsigned i = v.i;
    return (u16)((i + 0x7FFFu + ((i >> 16) & 1u)) >> 16);  // RNE
}

// ---- fp8 e4m3 helpers (HW cvt on gfx950; immarg operands are template params)
__device__ __forceinline__ u8 f32_fp8_sw(float f) {
    unsigned u = __float_as_uint(f);
    int s = (u >> 31) & 1;
    int exp = (int)((u >> 23) & 255) - 127;
    unsigned man = (u >> 20) & 7;
    if (exp < -6) return (u8)(s << 7);
    if (exp > 8) { exp = 8; man = 7; }
    return (u8)((s << 7) | ((exp + 7) << 3) | man);
}
__device__ __forceinline__ u8 f32_fp8(float f) {
#if __has_builtin(__builtin_amdgcn_cvt_pk_fp8_f32)
    return (u8)((unsigned)__builtin_amdgcn_cvt_pk_fp8_f32(f, f, 0, false) & 0xffu);
#else
    return f32_fp8_sw(f);
#endif
}
template <bool HI>
__device__ __forceinline__ unsigned pk2_fp8(float s0, float s1, unsigned old) {
#if __has_builtin(__builtin_amdgcn_cvt_pk_fp8_f32)
    return (unsigned)__builtin_amdgcn_cvt_pk_fp8_f32(s0, s1, (int)old, HI);
#else
    unsigned pair = (unsigned)f32_fp8_sw(s0) | ((unsigned)f32_fp8_sw(s1) << 8);
    return HI ? ((old & 0xffffu) | (pair << 16)) : ((old & 0xffff0000u) | pair);
#endif
}

// async global->LDS, 16B per lane, LDS dest = wave-uniform base + lane*16
__device__ __forceinline__ void async_cp16(const u16* g, u16* l) {
    __builtin_amdgcn_global_load_lds(
        (const __attribute__((address_space(1))) unsigned int*)g,
        (__attribute__((address_space(3))) unsigned int*)l, 16, 0, 0);
}

// ---------------- LayerNorm (+ optional residual-add + agg zeroing)
__global__ __launch_bounds__(256) void ln_fused(const float* __restrict__ xin,
                                                float* __restrict__ agg_io,
                                                float* __restrict__ xout,
                                                const float* __restrict__ g,
                                                const float* __restrict__ b,
                                                u16* __restrict__ h, int doAdd) {
    int row = blockIdx.x * 4 + (threadIdx.x >> 6);
    int lane = threadIdx.x & 63;
    const f32x4* x4 = (const f32x4*)(xin + (size_t)row * DD);
    f32x4 p = x4[lane * 2], q = x4[lane * 2 + 1];
    if (doAdd) {
        const f32x4* a4 = (const f32x4*)(agg_io + (size_t)row * DD);
        f32x4 pa = a4[lane * 2], qa = a4[lane * 2 + 1];
        #pragma unroll
        for (int i = 0; i < 4; ++i) { p[i] += pa[i]; q[i] += qa[i]; }
    }
    if (agg_io) {
        f32x4 z;
        #pragma unroll
        for (int i = 0; i < 4; ++i) z[i] = 0.f;
        f32x4* a4 = (f32x4*)(agg_io + (size_t)row * DD);
        a4[lane * 2] = z;
        a4[lane * 2 + 1] = z;
    }
    f32x4* xo = (f32x4*)(xout + (size_t)row * DD);
    xo[lane * 2] = p;
    xo[lane * 2 + 1] = q;
    float v[8];
    v[0] = p[0]; v[1] = p[1]; v[2] = p[2]; v[3] = p[3];
    v[4] = q[0]; v[5] = q[1]; v[6] = q[2]; v[7] = q[3];
    float s = 0.f, sq = 0.f;
    #pragma unroll
    for (int i = 0; i < 8; ++i) { s += v[i]; sq += v[i] * v[i]; }
    #pragma unroll
    for (int o = 32; o >= 1; o >>= 1) { s += __shfl_xor(s, o); sq += __shfl_xor(sq, o); }
    float mu = s * (1.f / DD);
    float var = sq * (1.f / DD) - mu * mu;
    float rs = rsqrtf(var + 1e-5f);
    int kb = lane * 8;
    u16x8 o8;
    #pragma unroll
    for (int i = 0; i < 8; ++i) o8[i] = f2bf((v[i] - mu) * rs * g[kb + i] + b[kb + i]);
    *(u16x8*)(h + (size_t)row * DD + kb) = o8;
}

// ---------------- counting sort by dst
__global__ void hist_kernel(const int* __restrict__ dst, int* __restrict__ cnt) {
    int e = blockIdx.x * 256 + threadIdx.x;
    if (e < EE) atomicAdd(&cnt[dst[e]], 1);
}

__global__ __launch_bounds__(1024) void scan_kernel(const int* __restrict__ cnt,
                                                    int* __restrict__ off,
                                                    int* __restrict__ cur) {
    __shared__ int part[1024];
    int t = threadIdx.x;
    int base = t * 8;
    int loc[8]; int s = 0;
    #pragma unroll
    for (int i = 0; i < 8; ++i) { loc[i] = s; s += cnt[base + i]; }
    part[t] = s;
    __syncthreads();
    for (int o = 1; o < 1024; o <<= 1) {
        int v = part[t];
        int u = (t >= o) ? part[t - o] : 0;
        __syncthreads();
        part[t] = v + u;
        __syncthreads();
    }
    int bx = (t > 0) ? part[t - 1] : 0;
    #pragma unroll
    for (int i = 0; i < 8; ++i) { off[base + i] = bx + loc[i]; cur[base + i] = bx + loc[i]; }
    if (t == 0) off[NN] = part[1023];
}

__global__ void scatter_kernel(const int* __restrict__ src, const int* __restrict__ dst,
                               int* __restrict__ cur, int* __restrict__ ssrc,
                               int* __restrict__ sdst) {
    int e = blockIdx.x * 256 + threadIdx.x;
    if (e < EE) {
        int d = dst[e];
        int p = atomicAdd(&cur[d], 1);
        ssrc[p] = src[e];
        sdst[p] = d;
    }
}

// ---------------- 2x fused cvt+transpose 512x512 fp32 -> bf16 [N][K] (FFN weights)
struct CvtJobs {
    const float* s[2];
    u16* d[2];
};
__global__ __launch_bounds__(256) void cvt_t2_kernel(CvtJobs jobs) {
    __shared__ u16 tile[32][33];
    const float* src = jobs.s[blockIdx.z];
    u16* dstp = jobs.d[blockIdx.z];
    int bk = blockIdx.x * 32, bn = blockIdx.y * 32;
    int tx = threadIdx.x & 31, ty = threadIdx.x >> 5;
    #pragma unroll
    for (int r = 0; r < 32; r += 8)
        tile[ty + r][tx] = f2bf(src[(size_t)(bk + ty + r) * 512 + bn + tx]);
    __syncthreads();
    #pragma unroll
    for (int r = 0; r < 32; r += 8)
        dstp[(size_t)(bn + ty + r) * 512 + bk + tx] = tile[tx][ty + r];
}

// W2 fp32 [L][512][512] -> fp8 e4m3 transposed+scaled: out[n][k] = fp8(16*W2[k][n])
__global__ __launch_bounds__(256) void cvt_w28_kernel(const float* __restrict__ W2g,
                                                      u8* __restrict__ dstg) {
    __shared__ float tile[32][33];
    const float* W2 = W2g + (size_t)blockIdx.z * 512 * 512;
    u8* dstp = dstg + (size_t)blockIdx.z * 512 * 512;
    int bk = blockIdx.x * 32, bn = blockIdx.y * 32;
    int tx = threadIdx.x & 31, ty = threadIdx.x >> 5;
    #pragma unroll
    for (int r = 0; r < 32; r += 8)
        tile[ty + r][tx] = W2[(size_t)(bk + ty + r) * 512 + bn + tx] * 16.f;
    __syncthreads();
    #pragma unroll
    for (int r = 0; r < 32; r += 8)
        dstp[(size_t)(bn + ty + r) * 512 + bk + tx] = f32_fp8(tile[tx][ty + r]);
}

// W1 fp32 [L][1024][512] -> Wcat^T bf16 [L][1024 rows][512]:
// rows 0..511 = (W1a - W1b)^T ; rows 512..1023 = W1b^T. z = layer.
__global__ __launch_bounds__(256) void cvt_w1_kernel(const float* __restrict__ W1g,
                                                     u16* __restrict__ dstg) {
    __shared__ u16 tile[32][33];
    const float* W1 = W1g + (size_t)blockIdx.z * 1024 * 512;
    u16* dstp = dstg + (size_t)blockIdx.z * 1024 * 512;
    int bk = blockIdx.x * 32, bn = blockIdx.y * 32;
    int tx = threadIdx.x & 31, ty = threadIdx.x >> 5;
    #pragma unroll
    for (int r = 0; r < 32; r += 8) {
        int k = bk + ty + r, n = bn + tx;
        float v = (n < 512) ? (W1[(size_t)k * 512 + n] - W1[(size_t)(k + 512) * 512 + n])
                            : W1[(size_t)(k + 512) * 512 + (n - 512)];
        tile[ty + r][tx] = f2bf(v);
    }
    __syncthreads();
    #pragma unroll
    for (int r = 0; r < 32; r += 8)
        dstp[(size_t)(bn + ty + r) * 512 + bk + tx] = tile[tx][ty + r];
}

// ---------------- async MFMA GEMM (bf16), 128x128 tile, 256 threads (2x2 waves)
// EMODE 0: relu(acc+bias)->bf16 ; 1: acc+bias+resid->fp32 ;
// EMODE 3: acc + (col<512 ? bias[col] : 0) -> bf16  (P-GEMM, b1 folded into Pa)
template <int EMODE>
__global__ __launch_bounds__(256) void gemm_async(
    const u16* __restrict__ A, const u16* __restrict__ BT,
    const float* __restrict__ bias, const float* __restrict__ resid,
    void* __restrict__ Cout, int K, int ldc) {
    __shared__ u16 lA[128 * 64];
    __shared__ u16 lB[128 * 64];
    const int tid = threadIdx.x;
    const int lane = tid & 63, wave = tid >> 6;
    const int wm = wave & 1, wn = wave >> 1;
    const int quad = lane >> 4, lm = lane & 15;
    const int tileM = blockIdx.x, tileN = blockIdx.y;

    const int g = (lane & 7) ^ (lane >> 3);
    const u16* ap[4];
    const u16* bp[4];
    u16* lad[4];
    u16* lbd[4];
    #pragma unroll
    for (int j = 0; j < 4; ++j) {
        int seg = wave * 4 + j;
        int rA = tileM * 128 + seg * 8 + (lane >> 3);
        int rB = tileN * 128 + seg * 8 + (lane >> 3);
        ap[j] = A + (size_t)rA * K + g * 8;
        bp[j] = BT + (size_t)rB * K + g * 8;
        lad[j] = lA + seg * 512;
        lbd[j] = lB + seg * 512;
    }

    f32x4 acc[4][4];
    #pragma unroll
    for (int mt = 0; mt < 4; ++mt)
        #pragma unroll
        for (int nt = 0; nt < 4; ++nt)
            #pragma unroll
            for (int j = 0; j < 4; ++j) acc[mt][nt][j] = 0.f;

    for (int kb = 0; kb < K; kb += 64) {
        #pragma unroll
        for (int j = 0; j < 4; ++j) {
            async_cp16(ap[j], lad[j]);
            async_cp16(bp[j], lbd[j]);
            ap[j] += 64;
            bp[j] += 64;
        }
        __syncthreads();
        #pragma unroll
        for (int kk = 0; kk < 64; kk += 32) {
            bf16x8 af[4], bfr[4];
            int gbase = (kk >> 3) + quad;
            #pragma unroll
            for (int mt = 0; mt < 4; ++mt) {
                int row = wm * 64 + mt * 16 + lm;
                af[mt] = *(const bf16x8*)(lA + row * 64 + ((gbase ^ (row & 7)) << 3));
            }
            #pragma unroll
            for (int nt = 0; nt < 4; ++nt) {
                int row = wn * 64 + nt * 16 + lm;
                bfr[nt] = *(const bf16x8*)(lB + row * 64 + ((gbase ^ (row & 7)) << 3));
            }
            #pragma unroll
            for (int mt = 0; mt < 4; ++mt)
                #pragma unroll
                for (int nt = 0; nt < 4; ++nt)
                    acc[mt][nt] = __builtin_amdgcn_mfma_f32_16x16x32_bf16(
                        af[mt], bfr[nt], acc[mt][nt], 0, 0, 0);
        }
        __syncthreads();
    }
    #pragma unroll
    for (int mt = 0; mt < 4; ++mt) {
        #pragma unroll
        for (int nt = 0; nt < 4; ++nt) {
            int col = tileN * 128 + wn * 64 + nt * 16 + lm;
            float bv;
            if (EMODE == 3) bv = (col < 512) ? bias[col] : 0.f;
            else bv = bias[col];
            #pragma unroll
            for (int j = 0; j < 4; ++j) {
                int grow = tileM * 128 + wm * 64 + mt * 16 + quad * 4 + j;
                float v = acc[mt][nt][j] + bv;
                if (EMODE == 0) {
                    ((u16*)Cout)[(size_t)grow * ldc + col] = f2bf(fmaxf(v, 0.f));
                } else if (EMODE == 1) {
                    ((float*)Cout)[(size_t)grow * ldc + col] =
                        v + resid[(size_t)grow * ldc + col];
                } else {
                    ((u16*)Cout)[(size_t)grow * ldc + col] = f2bf(v);
                }
            }
        }
    }
}

// ---------------- fused edge GEMM (fp8 MFMA), tile 128 edges x 256 cols,
// 512 thr (8 waves, wave-tile 64x64). t = relu(Pa[dst]+Pb[src]) packed to fp8
// e4m3 in the combine; W2 pre-scaled x16 and fp8 -> GEMM2 runs on
// v_mfma_f32_16x16x32_fp8_fp8 (same rate as bf16, HALF the LDS/staging bytes
// -- round-11 attack on the per-iter pipe work; 16 waves/CU is the register
// ceiling so more occupancy is impossible). LDS rows padded to 72 B: 16-lane
// frag reads hit 16 distinct banks (r*18 mod 32 is a permutation), no XOR
// swizzle needed. Epilogue: acc/16 + b2, relu -> cbuf -> run-max -> atomicMax.
__global__ __launch_bounds__(512, 4) void gemm_edge(
    const u16* __restrict__ P, const int* __restrict__ ssrc,
    const int* __restrict__ sdst, const u8* __restrict__ W28T,
    const float* __restrict__ b2, float* __restrict__ agg) {
    __shared__ u16 smem[16896];  // 33.8KB: lA 128x36 + lB 256x36; cbuf 64x264 aliases
    __shared__ int nid_l[128];
    u16* lA = smem;
    u16* lB = smem + 128 * LSTR;
    const int tid = threadIdx.x;
    const int lane = tid & 63, wave = tid >> 6;  // 8 waves
    const int wm = wave & 1, wn = wave >> 1;     // wave tile 64(M) x 64(N)
    const int quad = lane >> 4, lm = lane & 15;
    const int tileN = blockIdx.x;                // col half
    const int ebase = blockIdx.y * 128;

    if (tid < 128) nid_l[tid] = sdst[ebase + tid];

    const int g = lane & 7;  // K-granule 0..7 (8 fp8 / 8 bf16 elements)
    // A staging: 2 segments of 8 rows per wave; P is [N][1024] bf16 (b1 in Pa)
    int aoff[2], boff[2];
    u16* lout[2];
    #pragma unroll
    for (int j = 0; j < 2; ++j) {
        int seg = wave * 2 + j;
        int row = seg * 8 + (lane >> 3);
        int dn = sdst[ebase + row];
        int sn = ssrc[ebase + row];
        aoff[j] = dn * 1024 + g * 8;
        boff[j] = sn * 1024 + 512 + g * 8;
        lout[j] = lA + row * LSTR + g * 4;  // 8 fp8 = 4 u16
    }
    // B staging: 4 passes of 64 rows; thread -> (row = tid>>3, granule = tid&7)
    const int brow = tid >> 3;
    const int bg = tid & 7;

    f32x4 acc[4][4];
    #pragma unroll
    for (int mt = 0; mt < 4; ++mt)
        #pragma unroll
        for (int nt = 0; nt < 4; ++nt)
            #pragma unroll
            for (int j = 0; j < 4; ++j) acc[mt][nt][j] = 0.f;

    for (int kb = 0; kb < 512; kb += 64) {
        // B loads first (L2-hot 256KB stream), 8 B/lane x 4
        uint2 bw[4];
        #pragma unroll
        for (int j = 0; j < 4; ++j) {
            int lrow = j * 64 + brow;
            bw[j] = *(const uint2*)(W28T + (size_t)(tileN * 256 + lrow) * 512 + kb +
                                    bg * 8);
        }
        // A gathers (bf16, dst-sorted Pa mostly L2-hot)
        u16x8 ga[2], gb[2];
        #pragma unroll
        for (int j = 0; j < 2; ++j) {
            ga[j] = *(const u16x8*)(P + aoff[j] + kb);
            gb[j] = *(const u16x8*)(P + boff[j] + kb);
        }
        // combine: t = relu(Pa + Pb) -> fp8 x8 -> lA
        #pragma unroll
        for (int j = 0; j < 2; ++j) {
            union { u16x8 v; unsigned w[4]; } ua, ub;
            ua.v = ga[j];
            ub.v = gb[j];
            f32x2 s[4];
            #pragma unroll
            for (int q = 0; q < 4; ++q) {
                f32x2 a, c;
                a[0] = __uint_as_float(ua.w[q] << 16);
                a[1] = __uint_as_float(ua.w[q] & 0xffff0000u);
                c[0] = __uint_as_float(ub.w[q] << 16);
                c[1] = __uint_as_float(ub.w[q] & 0xffff0000u);
                f32x2 t = a + c;
                t[0] = fmaxf(t[0], 0.f);
                t[1] = fmaxf(t[1], 0.f);
                s[q] = t;
            }
            unsigned d0 = pk2_fp8<false>(s[0][0], s[0][1], 0u);
            d0 = pk2_fp8<true>(s[1][0], s[1][1], d0);
            unsigned d1 = pk2_fp8<false>(s[2][0], s[2][1], 0u);
            d1 = pk2_fp8<true>(s[3][0], s[3][1], d1);
            *(uint2*)lout[j] = make_uint2(d0, d1);
        }
        // B -> LDS
        #pragma unroll
        for (int j = 0; j < 4; ++j)
            *(uint2*)(lB + (j * 64 + brow) * LSTR + bg * 4) = bw[j];
        __syncthreads();
        #pragma unroll
        for (int kk = 0; kk < 64; kk += 32) {
            long af[4], bf[4];
            int gq = (kk >> 3) + quad;  // granule 0..7
            #pragma unroll
            for (int mt = 0; mt < 4; ++mt) {
                int row = wm * 64 + mt * 16 + lm;
                af[mt] = *(const long*)(lA + row * LSTR + gq * 4);
            }
            #pragma unroll
            for (int nt = 0; nt < 4; ++nt) {
                int row = wn * 64 + nt * 16 + lm;
                bf[nt] = *(const long*)(lB + row * LSTR + gq * 4);
            }
            #pragma unroll
            for (int mt = 0; mt < 4; ++mt)
                #pragma unroll
                for (int nt = 0; nt < 4; ++nt)
                    acc[mt][nt] = __builtin_amdgcn_mfma_f32_16x16x32_fp8_fp8(
                        af[mt], bf[nt], acc[mt][nt], 0, 0, 0);
        }
        __syncthreads();
    }

    // epilogue: 2 passes of 64 rows; cbuf 64 x 264 u16 (aliases lA/lB exactly)
    u16* cbuf = smem;
    for (int p = 0; p < 2; ++p) {
        if (wm == p) {
            #pragma unroll
            for (int nt = 0; nt < 4; ++nt) {
                int lcol = wn * 64 + nt * 16 + lm;
                float bv = b2[tileN * 256 + lcol];
                #pragma unroll
                for (int mt = 0; mt < 4; ++mt) {
                    #pragma unroll
                    for (int j2 = 0; j2 < 4; ++j2) {
                        int row = mt * 16 + quad * 4 + j2;
                        cbuf[row * 264 + lcol] =
                            f2bf(fmaxf(acc[mt][nt][j2] * 0.0625f + bv, 0.f));
                    }
                }
            }
        }
        __syncthreads();
        {
            int lcol = tid & 255;
            int gcol = tileN * 256 + lcol;
            int r0 = (tid >> 8) * 32;
            int gr0 = p * 64 + r0;
            int cur = nid_l[gr0];
            float run = bf2f(cbuf[r0 * 264 + lcol]);
            for (int r = 1; r < 32; ++r) {
                int nd = nid_l[gr0 + r];
                float v = bf2f(cbuf[(r0 + r) * 264 + lcol]);
                if (nd != cur) {
                    atomicMax((unsigned int*)&agg[(size_t)cur * DD + gcol],
                              __float_as_uint(run));
                    cur = nd;
                    run = v;
                } else {
                    run = fmaxf(run, v);
                }
            }
            atomicMax((unsigned int*)&agg[(size_t)cur * DD + gcol],
                      __float_as_uint(run));
        }
        __syncthreads();
    }
}

// ---------------- gather selected rows with residual add: xs[i] = x[r] + agg[r]
__global__ __launch_bounds__(128) void gather_fused(const float* __restrict__ x,
                                                    const float* __restrict__ agg,
                                                    const int* __restrict__ sel,
                                                    float* __restrict__ xs) {
    int i = blockIdx.x;
    int b = i >> 7;
    int r = b * NPG + sel[i];
    const f32x4* srcp = (const f32x4*)(x + (size_t)r * DD);
    const f32x4* aggp = (const f32x4*)(agg + (size_t)r * DD);
    f32x4 v = srcp[threadIdx.x];
    f32x4 a = aggp[threadIdx.x];
    #pragma unroll
    for (int j = 0; j < 4; ++j) v[j] += a[j];
    ((f32x4*)(xs + (size_t)i * DD))[threadIdx.x] = v;
}

extern "C" void kernel_launch(void* const* d_in, const int* in_sizes, int n_in,
                              void* d_out, int out_size, void* d_ws, size_t ws_size,
                              hipStream_t stream) {
    const float* x_in = (const float*)d_in[0];
    const int* ei = (const int*)d_in[1];
    const int* sel = (const int*)d_in[2];
    const float* W1 = (const float*)d_in[4];
    const float* b1 = (const float*)d_in[5];
    const float* W2 = (const float*)d_in[6];
    const float* b2 = (const float*)d_in[7];
    const float* g1 = (const float*)d_in[8];
    const float* be1 = (const float*)d_in[9];
    const float* g2 = (const float*)d_in[10];
    const float* be2 = (const float*)d_in[11];
    const float* fW1 = (const float*)d_in[12];
    const float* fb1 = (const float*)d_in[13];
    const float* fW2 = (const float*)d_in[14];
    const float* fb2 = (const float*)d_in[15];
    float* out = (float*)d_out;

    char* w = (char*)d_ws;
    size_t off = 0;
    auto alloc = [&](size_t bytes) -> char* {
        char* p = w + off;
        off += (bytes + 255) & ~(size_t)255;
        return p;
    };
    float* xbuf = (float*)alloc((size_t)NN * DD * 4);
    float* agg  = (float*)alloc((size_t)NN * DD * 4);
    u16* h      = (u16*)alloc((size_t)NN * DD * 2);
    u16* P      = (u16*)alloc((size_t)NN * 1024 * 2);
    u16* W1T    = (u16*)alloc((size_t)LL * 1024 * DD * 2);
    u8* W28T    = (u8*)alloc((size_t)LL * DD * DD);
    u16* FW1T   = (u16*)alloc((size_t)DD * DD * 2);
    u16* FW2T   = (u16*)alloc((size_t)DD * DD * 2);
    int* cnt    = (int*)alloc((size_t)NN * 4);
    int* offs   = (int*)alloc((size_t)(NN + 1) * 4);
    int* cur    = (int*)alloc((size_t)NN * 4);
    int* ssrc   = (int*)alloc((size_t)EE * 4);
    int* sdst   = (int*)alloc((size_t)EE * 4);
    float* xs   = (float*)alloc((size_t)BBATCH * SSEL * DD * 4);
    u16* hs     = (u16*)alloc((size_t)BBATCH * SSEL * DD * 2);
    u16* uu     = (u16*)alloc((size_t)BBATCH * SSEL * DD * 2);

    const int* esrc = ei;       // edge_index[0] = x_j
    const int* edst = ei + EE;  // edge_index[1] = x_i / aggregation index

    (void)hipMemsetAsync(cnt, 0, (size_t)NN * 4, stream);
    hist_kernel<<<EE / 256, 256, 0, stream>>>(edst, cnt);
    scan_kernel<<<1, 1024, 0, stream>>>(cnt, offs, cur);
    scatter_kernel<<<EE / 256, 256, 0, stream>>>(esrc, edst, cur, ssrc, sdst);

    // weight conversions
    cvt_w1_kernel<<<dim3(16, 32, LL), 256, 0, stream>>>(W1, W1T);
    cvt_w28_kernel<<<dim3(16, 16, LL), 256, 0, stream>>>(W2, W28T);
    {
        CvtJobs jobs;
        jobs.s[0] = fW1;
        jobs.s[1] = fW2;
        jobs.d[0] = FW1T;
        jobs.d[1] = FW2T;
        cvt_t2_kernel<<<dim3(16, 16, 2), 256, 0, stream>>>(jobs);
    }

    for (int l = 0; l < LL; ++l) {
        // x_l = x_{l-1} + agg ; h = LN(x_l) ; agg <- 0 for this layer's atomics
        ln_fused<<<NN / 4, 256, 0, stream>>>(l == 0 ? x_in : xbuf, agg, xbuf, g1, be1,
                                             h, l > 0 ? 1 : 0);
        // P = h @ [W1a-W1b | W1b] + [b1 | 0]   [8192 x 1024] bf16
        {
            dim3 grid(NN / 128, 1024 / 128);
            gemm_async<3><<<grid, 256, 0, stream>>>(
                h, W1T + (size_t)l * 1024 * DD, b1 + (size_t)l * DD, nullptr, P, DD,
                1024);
        }
        // fused: edge-combine(fp8) + fp8 GEMM2 + relu + segmax-atomics into agg
        gemm_edge<<<dim3(2, EE / 128), 512, 0, stream>>>(
            P, ssrc, sdst, W28T + (size_t)l * DD * DD, b2 + (size_t)l * DD, agg);
    }

    gather_fused<<<BBATCH * SSEL, 128, 0, stream>>>(xbuf, agg, sel, xs);
    ln_fused<<<BBATCH * SSEL / 4, 256, 0, stream>>>(xs, nullptr, xs, g2, be2, hs, 0);
    dim3 gridf(BBATCH * SSEL / 128, DD / 128);
    gemm_async<0><<<gridf, 256, 0, stream>>>(hs, FW1T, fb1, nullptr, uu, DD, DD);
    gemm_async<1><<<gridf, 256, 0, stream>>>(uu, FW2T, fb2, xs, out, DD, DD);
}

// Round 12
// 568.839 us; speedup vs baseline: 1.0501x; 1.0284x over previous
//
#include <hip/hip_runtime.h>
#include <stdint.h>

#define NN 8192
#define DD 512
#define EE 131072
#define BBATCH 16
#define NPG 512
#define SSEL 128
#define LL 3

typedef unsigned short u16;
typedef unsigned char u8;
typedef __bf16 bf16x8 __attribute__((ext_vector_type(8)));
typedef float f32x4 __attribute__((ext_vector_type(4)));
typedef float f32x2 __attribute__((ext_vector_type(2)));
typedef u16 u16x8 __attribute__((ext_vector_type(8)));

__device__ __forceinline__ float bf2f(u16 u) {
    union { unsigned i; float f; } v; v.i = ((unsigned)u) << 16; return v.f;
}
__device__ __forceinline__ u16 f2bf(float f) {
    union { unsigned i; float f; } v; v.f = f;
    unsigned i = v.i;
    return (u16)((i + 0x7FFFu + ((i >> 16) & 1u)) >> 16);  // RNE
}

// ---- fp8 e4m3 helpers (HW cvt on gfx950; immarg operands are template params)
__device__ __forceinline__ u8 f32_fp8_sw(float f) {
    unsigned u = __float_as_uint(f);
    int s = (u >> 31) & 1;
    int exp = (int)((u >> 23) & 255) - 127;
    unsigned man = (u >> 20) & 7;
    if (exp < -6) return (u8)(s << 7);
    if (exp > 8) { exp = 8; man = 7; }
    return (u8)((s << 7) | ((exp + 7) << 3) | man);
}
__device__ __forceinline__ u8 f32_fp8(float f) {
#if __has_builtin(__builtin_amdgcn_cvt_pk_fp8_f32)
    return (u8)((unsigned)__builtin_amdgcn_cvt_pk_fp8_f32(f, f, 0, false) & 0xffu);
#else
    return f32_fp8_sw(f);
#endif
}
template <bool HI>
__device__ __forceinline__ unsigned pk2_fp8(float s0, float s1, unsigned old) {
#if __has_builtin(__builtin_amdgcn_cvt_pk_fp8_f32)
    return (unsigned)__builtin_amdgcn_cvt_pk_fp8_f32(s0, s1, (int)old, HI);
#else
    unsigned pair = (unsigned)f32_fp8_sw(s0) | ((unsigned)f32_fp8_sw(s1) << 8);
    return HI ? ((old & 0xffffu) | (pair << 16)) : ((old & 0xffff0000u) | pair);
#endif
}

// async global->LDS, 16B per lane, LDS dest = wave-uniform base + lane*16
__device__ __forceinline__ void async_cp16(const u16* g, u16* l) {
    __builtin_amdgcn_global_load_lds(
        (const __attribute__((address_space(1))) unsigned int*)g,
        (__attribute__((address_space(3))) unsigned int*)l, 16, 0, 0);
}

// ---------------- LayerNorm (+ optional residual-add + agg zeroing)
__global__ __launch_bounds__(256) void ln_fused(const float* __restrict__ xin,
                                                float* __restrict__ agg_io,
                                                float* __restrict__ xout,
                                                const float* __restrict__ g,
                                                const float* __restrict__ b,
                                                u16* __restrict__ h, int doAdd) {
    int row = blockIdx.x * 4 + (threadIdx.x >> 6);
    int lane = threadIdx.x & 63;
    const f32x4* x4 = (const f32x4*)(xin + (size_t)row * DD);
    f32x4 p = x4[lane * 2], q = x4[lane * 2 + 1];
    if (doAdd) {
        const f32x4* a4 = (const f32x4*)(agg_io + (size_t)row * DD);
        f32x4 pa = a4[lane * 2], qa = a4[lane * 2 + 1];
        #pragma unroll
        for (int i = 0; i < 4; ++i) { p[i] += pa[i]; q[i] += qa[i]; }
    }
    if (agg_io) {
        f32x4 z;
        #pragma unroll
        for (int i = 0; i < 4; ++i) z[i] = 0.f;
        f32x4* a4 = (f32x4*)(agg_io + (size_t)row * DD);
        a4[lane * 2] = z;
        a4[lane * 2 + 1] = z;
    }
    f32x4* xo = (f32x4*)(xout + (size_t)row * DD);
    xo[lane * 2] = p;
    xo[lane * 2 + 1] = q;
    float v[8];
    v[0] = p[0]; v[1] = p[1]; v[2] = p[2]; v[3] = p[3];
    v[4] = q[0]; v[5] = q[1]; v[6] = q[2]; v[7] = q[3];
    float s = 0.f, sq = 0.f;
    #pragma unroll
    for (int i = 0; i < 8; ++i) { s += v[i]; sq += v[i] * v[i]; }
    #pragma unroll
    for (int o = 32; o >= 1; o >>= 1) { s += __shfl_xor(s, o); sq += __shfl_xor(sq, o); }
    float mu = s * (1.f / DD);
    float var = sq * (1.f / DD) - mu * mu;
    float rs = rsqrtf(var + 1e-5f);
    int kb = lane * 8;
    u16x8 o8;
    #pragma unroll
    for (int i = 0; i < 8; ++i) o8[i] = f2bf((v[i] - mu) * rs * g[kb + i] + b[kb + i]);
    *(u16x8*)(h + (size_t)row * DD + kb) = o8;
}

// ---------------- counting sort by dst
__global__ void hist_kernel(const int* __restrict__ dst, int* __restrict__ cnt) {
    int e = blockIdx.x * 256 + threadIdx.x;
    if (e < EE) atomicAdd(&cnt[dst[e]], 1);
}

__global__ __launch_bounds__(1024) void scan_kernel(const int* __restrict__ cnt,
                                                    int* __restrict__ off,
                                                    int* __restrict__ cur) {
    __shared__ int part[1024];
    int t = threadIdx.x;
    int base = t * 8;
    int loc[8]; int s = 0;
    #pragma unroll
    for (int i = 0; i < 8; ++i) { loc[i] = s; s += cnt[base + i]; }
    part[t] = s;
    __syncthreads();
    for (int o = 1; o < 1024; o <<= 1) {
        int v = part[t];
        int u = (t >= o) ? part[t - o] : 0;
        __syncthreads();
        part[t] = v + u;
        __syncthreads();
    }
    int bx = (t > 0) ? part[t - 1] : 0;
    #pragma unroll
    for (int i = 0; i < 8; ++i) { off[base + i] = bx + loc[i]; cur[base + i] = bx + loc[i]; }
    if (t == 0) off[NN] = part[1023];
}

__global__ void scatter_kernel(const int* __restrict__ src, const int* __restrict__ dst,
                               int* __restrict__ cur, int* __restrict__ ssrc,
                               int* __restrict__ sdst) {
    int e = blockIdx.x * 256 + threadIdx.x;
    if (e < EE) {
        int d = dst[e];
        int p = atomicAdd(&cur[d], 1);
        ssrc[p] = src[e];
        sdst[p] = d;
    }
}

// ---------------- 2x fused cvt+transpose 512x512 fp32 -> bf16 [N][K] (FFN weights)
struct CvtJobs {
    const float* s[2];
    u16* d[2];
};
__global__ __launch_bounds__(256) void cvt_t2_kernel(CvtJobs jobs) {
    __shared__ u16 tile[32][33];
    const float* src = jobs.s[blockIdx.z];
    u16* dstp = jobs.d[blockIdx.z];
    int bk = blockIdx.x * 32, bn = blockIdx.y * 32;
    int tx = threadIdx.x & 31, ty = threadIdx.x >> 5;
    #pragma unroll
    for (int r = 0; r < 32; r += 8)
        tile[ty + r][tx] = f2bf(src[(size_t)(bk + ty + r) * 512 + bn + tx]);
    __syncthreads();
    #pragma unroll
    for (int r = 0; r < 32; r += 8)
        dstp[(size_t)(bn + ty + r) * 512 + bk + tx] = tile[tx][ty + r];
}

// W2 fp32 [L][512][512] -> fp8 e4m3 transposed+scaled: out[n][k] = fp8(16*W2[k][n])
__global__ __launch_bounds__(256) void cvt_w28_kernel(const float* __restrict__ W2g,
                                                      u8* __restrict__ dstg) {
    __shared__ float tile[32][33];
    const float* W2 = W2g + (size_t)blockIdx.z * 512 * 512;
    u8* dstp = dstg + (size_t)blockIdx.z * 512 * 512;
    int bk = blockIdx.x * 32, bn = blockIdx.y * 32;
    int tx = threadIdx.x & 31, ty = threadIdx.x >> 5;
    #pragma unroll
    for (int r = 0; r < 32; r += 8)
        tile[ty + r][tx] = W2[(size_t)(bk + ty + r) * 512 + bn + tx] * 16.f;
    __syncthreads();
    #pragma unroll
    for (int r = 0; r < 32; r += 8)
        dstp[(size_t)(bn + ty + r) * 512 + bk + tx] = f32_fp8(tile[tx][ty + r]);
}

// W1 fp32 [L][1024][512] -> Wcat^T bf16 [L][1024 rows][512]:
// rows 0..511 = (W1a - W1b)^T ; rows 512..1023 = W1b^T. z = layer.
__global__ __launch_bounds__(256) void cvt_w1_kernel(const float* __restrict__ W1g,
                                                     u16* __restrict__ dstg) {
    __shared__ u16 tile[32][33];
    const float* W1 = W1g + (size_t)blockIdx.z * 1024 * 512;
    u16* dstp = dstg + (size_t)blockIdx.z * 1024 * 512;
    int bk = blockIdx.x * 32, bn = blockIdx.y * 32;
    int tx = threadIdx.x & 31, ty = threadIdx.x >> 5;
    #pragma unroll
    for (int r = 0; r < 32; r += 8) {
        int k = bk + ty + r, n = bn + tx;
        float v = (n < 512) ? (W1[(size_t)k * 512 + n] - W1[(size_t)(k + 512) * 512 + n])
                            : W1[(size_t)(k + 512) * 512 + (n - 512)];
        tile[ty + r][tx] = f2bf(v);
    }
    __syncthreads();
    #pragma unroll
    for (int r = 0; r < 32; r += 8)
        dstp[(size_t)(bn + ty + r) * 512 + bk + tx] = tile[tx][ty + r];
}

// ---------------- async MFMA GEMM (bf16), 128x128 tile, 256 threads (2x2 waves)
// EMODE 0: relu(acc+bias)->bf16 ; 1: acc+bias+resid->fp32 ;
// EMODE 3: acc + (col<512 ? bias[col] : 0) -> bf16  (P-GEMM, b1 folded into Pa)
template <int EMODE>
__global__ __launch_bounds__(256) void gemm_async(
    const u16* __restrict__ A, const u16* __restrict__ BT,
    const float* __restrict__ bias, const float* __restrict__ resid,
    void* __restrict__ Cout, int K, int ldc) {
    __shared__ u16 lA[128 * 64];
    __shared__ u16 lB[128 * 64];
    const int tid = threadIdx.x;
    const int lane = tid & 63, wave = tid >> 6;
    const int wm = wave & 1, wn = wave >> 1;
    const int quad = lane >> 4, lm = lane & 15;
    const int tileM = blockIdx.x, tileN = blockIdx.y;

    const int g = (lane & 7) ^ (lane >> 3);
    const u16* ap[4];
    const u16* bp[4];
    u16* lad[4];
    u16* lbd[4];
    #pragma unroll
    for (int j = 0; j < 4; ++j) {
        int seg = wave * 4 + j;
        int rA = tileM * 128 + seg * 8 + (lane >> 3);
        int rB = tileN * 128 + seg * 8 + (lane >> 3);
        ap[j] = A + (size_t)rA * K + g * 8;
        bp[j] = BT + (size_t)rB * K + g * 8;
        lad[j] = lA + seg * 512;
        lbd[j] = lB + seg * 512;
    }

    f32x4 acc[4][4];
    #pragma unroll
    for (int mt = 0; mt < 4; ++mt)
        #pragma unroll
        for (int nt = 0; nt < 4; ++nt)
            #pragma unroll
            for (int j = 0; j < 4; ++j) acc[mt][nt][j] = 0.f;

    for (int kb = 0; kb < K; kb += 64) {
        #pragma unroll
        for (int j = 0; j < 4; ++j) {
            async_cp16(ap[j], lad[j]);
            async_cp16(bp[j], lbd[j]);
            ap[j] += 64;
            bp[j] += 64;
        }
        __syncthreads();
        #pragma unroll
        for (int kk = 0; kk < 64; kk += 32) {
            bf16x8 af[4], bfr[4];
            int gbase = (kk >> 3) + quad;
            #pragma unroll
            for (int mt = 0; mt < 4; ++mt) {
                int row = wm * 64 + mt * 16 + lm;
                af[mt] = *(const bf16x8*)(lA + row * 64 + ((gbase ^ (row & 7)) << 3));
            }
            #pragma unroll
            for (int nt = 0; nt < 4; ++nt) {
                int row = wn * 64 + nt * 16 + lm;
                bfr[nt] = *(const bf16x8*)(lB + row * 64 + ((gbase ^ (row & 7)) << 3));
            }
            #pragma unroll
            for (int mt = 0; mt < 4; ++mt)
                #pragma unroll
                for (int nt = 0; nt < 4; ++nt)
                    acc[mt][nt] = __builtin_amdgcn_mfma_f32_16x16x32_bf16(
                        af[mt], bfr[nt], acc[mt][nt], 0, 0, 0);
        }
        __syncthreads();
    }
    #pragma unroll
    for (int mt = 0; mt < 4; ++mt) {
        #pragma unroll
        for (int nt = 0; nt < 4; ++nt) {
            int col = tileN * 128 + wn * 64 + nt * 16 + lm;
            float bv;
            if (EMODE == 3) bv = (col < 512) ? bias[col] : 0.f;
            else bv = bias[col];
            #pragma unroll
            for (int j = 0; j < 4; ++j) {
                int grow = tileM * 128 + wm * 64 + mt * 16 + quad * 4 + j;
                float v = acc[mt][nt][j] + bv;
                if (EMODE == 0) {
                    ((u16*)Cout)[(size_t)grow * ldc + col] = f2bf(fmaxf(v, 0.f));
                } else if (EMODE == 1) {
                    ((float*)Cout)[(size_t)grow * ldc + col] =
                        v + resid[(size_t)grow * ldc + col];
                } else {
                    ((u16*)Cout)[(size_t)grow * ldc + col] = f2bf(v);
                }
            }
        }
    }
}

// ---------------- fused edge GEMM (fp8 MFMA), tile 64 edges x 512 cols,
// 512 thr (8 waves, wave-tile 64Mx64N, 1x8): the edge combine + Pa/Pb gathers
// happen ONCE per edge per layer (round-7/11 did them twice via the col split).
// LDS is granule-pair-major: addr(row,g) = (g>>1)*R*16 + row*16 + (g&1)*8 ->
// frag-read bank = 4*row mod 32 = 2-way aliasing only (free, m136). Fixes
// round-11's 3.1M-cycle conflict bug. lA 4KB + lB 32KB = 36.9KB -> 2 blocks/CU
// at the 16-wave register ceiling. Epilogue: acc/16 + b2, relu -> cbuf (stride
// 264) -> run-max -> atomicMax(agg).
__global__ __launch_bounds__(512, 4) void gemm_edge(
    const u16* __restrict__ P, const int* __restrict__ ssrc,
    const int* __restrict__ sdst, const u8* __restrict__ W28T,
    const float* __restrict__ b2, float* __restrict__ agg) {
    __shared__ u16 smem[2048 + 16384];  // lA 4KB + lB 32KB; cbuf 64x264 aliases
    __shared__ int nid_l[64];
    u16* lA = smem;
    u16* lB = smem + 2048;
    const int tid = threadIdx.x;
    const int lane = tid & 63, wave = tid >> 6;  // 8 waves
    const int wn = wave;                         // cols wn*64..+64, rows 0..63
    const int quad = lane >> 4, lm = lane & 15;
    const int ebase = blockIdx.x * 64;

    if (tid < 64) nid_l[tid] = sdst[ebase + tid];

    // A combine task: row = tid>>3 (0..63), k-granule ag = tid&7 (8 elems)
    const int arow = tid >> 3;
    const int ag = tid & 7;
    const int dn = sdst[ebase + arow];
    const int sn = ssrc[ebase + arow];
    const int aoff = dn * 1024 + ag * 8;
    const int boff = sn * 1024 + 512 + ag * 8;
    u16* aout = lA + (ag >> 1) * 512 + arow * 8 + (ag & 1) * 4;

    // B staging task: per wave 16 rows x 4 granule-pairs, 4 passes of 128 rows
    const int brow0 = (wave << 4) + (lane >> 2);  // + j*128
    const int bgp = lane & 3;

    f32x4 acc[4][4];
    #pragma unroll
    for (int mt = 0; mt < 4; ++mt)
        #pragma unroll
        for (int nt = 0; nt < 4; ++nt)
            #pragma unroll
            for (int j = 0; j < 4; ++j) acc[mt][nt][j] = 0.f;

    for (int kb = 0; kb < 512; kb += 64) {
        // B loads (L2-hot W2 stream): 4x 16B per thread
        uint4 bw[4];
        #pragma unroll
        for (int j = 0; j < 4; ++j)
            bw[j] = *(const uint4*)(W28T + (size_t)(j * 128 + brow0) * 512 + kb +
                                    bgp * 16);
        // A gathers (bf16 P; dst-sorted Pa L2/L1-hot, Pb random)
        u16x8 ga = *(const u16x8*)(P + aoff + kb);
        u16x8 gb = *(const u16x8*)(P + boff + kb);
        // combine: t = relu(Pa + Pb) -> 8x fp8 -> lA (granule-pair-major)
        {
            union { u16x8 v; unsigned w[4]; } ua, ub;
            ua.v = ga;
            ub.v = gb;
            f32x2 s[4];
            #pragma unroll
            for (int q = 0; q < 4; ++q) {
                f32x2 a, c;
                a[0] = __uint_as_float(ua.w[q] << 16);
                a[1] = __uint_as_float(ua.w[q] & 0xffff0000u);
                c[0] = __uint_as_float(ub.w[q] << 16);
                c[1] = __uint_as_float(ub.w[q] & 0xffff0000u);
                f32x2 t = a + c;
                t[0] = fmaxf(t[0], 0.f);
                t[1] = fmaxf(t[1], 0.f);
                s[q] = t;
            }
            unsigned d0 = pk2_fp8<false>(s[0][0], s[0][1], 0u);
            d0 = pk2_fp8<true>(s[1][0], s[1][1], d0);
            unsigned d1 = pk2_fp8<false>(s[2][0], s[2][1], 0u);
            d1 = pk2_fp8<true>(s[3][0], s[3][1], d1);
            *(uint2*)aout = make_uint2(d0, d1);
        }
        // B -> LDS granule-pair-major: lB[gp][row], 16B units
        #pragma unroll
        for (int j = 0; j < 4; ++j)
            *(uint4*)(lB + bgp * 4096 + (size_t)(j * 128 + brow0) * 8) = bw[j];
        __syncthreads();
        #pragma unroll
        for (int kk = 0; kk < 64; kk += 32) {
            long af[4], bf[4];
            int gq = (kk >> 3) + quad;  // granule 0..7
            int gph = gq >> 1, gl = (gq & 1) * 4;
            #pragma unroll
            for (int mt = 0; mt < 4; ++mt) {
                int row = mt * 16 + lm;
                af[mt] = *(const long*)(lA + gph * 512 + row * 8 + gl);
            }
            #pragma unroll
            for (int nt = 0; nt < 4; ++nt) {
                int row = wn * 64 + nt * 16 + lm;
                bf[nt] = *(const long*)(lB + gph * 4096 + row * 8 + gl);
            }
            #pragma unroll
            for (int mt = 0; mt < 4; ++mt)
                #pragma unroll
                for (int nt = 0; nt < 4; ++nt)
                    acc[mt][nt] = __builtin_amdgcn_mfma_f32_16x16x32_fp8_fp8(
                        af[mt], bf[nt], acc[mt][nt], 0, 0, 0);
        }
        __syncthreads();
    }

    // epilogue: 2 col-half passes; cbuf 64 x 264 u16 (33.8KB, aliases lA/lB)
    u16* cbuf = smem;
    for (int p = 0; p < 2; ++p) {
        if ((wave >> 2) == p) {
            int lcol0 = (wave & 3) * 64;
            #pragma unroll
            for (int nt = 0; nt < 4; ++nt) {
                int lcol = lcol0 + nt * 16 + lm;
                float bv = b2[p * 256 + lcol];
                #pragma unroll
                for (int mt = 0; mt < 4; ++mt) {
                    #pragma unroll
                    for (int j2 = 0; j2 < 4; ++j2) {
                        int row = mt * 16 + quad * 4 + j2;
                        cbuf[row * 264 + lcol] =
                            f2bf(fmaxf(acc[mt][nt][j2] * 0.0625f + bv, 0.f));
                    }
                }
            }
        }
        __syncthreads();
        {
            int lcol = tid & 255;
            int gcol = p * 256 + lcol;
            int r0 = (tid >> 8) * 32;
            int cur = nid_l[r0];
            float run = bf2f(cbuf[r0 * 264 + lcol]);
            for (int r = 1; r < 32; ++r) {
                int nd = nid_l[r0 + r];
                float v = bf2f(cbuf[(r0 + r) * 264 + lcol]);
                if (nd != cur) {
                    atomicMax((unsigned int*)&agg[(size_t)cur * DD + gcol],
                              __float_as_uint(run));
                    cur = nd;
                    run = v;
                } else {
                    run = fmaxf(run, v);
                }
            }
            atomicMax((unsigned int*)&agg[(size_t)cur * DD + gcol],
                      __float_as_uint(run));
        }
        __syncthreads();
    }
}

// ---------------- gather selected rows with residual add: xs[i] = x[r] + agg[r]
__global__ __launch_bounds__(128) void gather_fused(const float* __restrict__ x,
                                                    const float* __restrict__ agg,
                                                    const int* __restrict__ sel,
                                                    float* __restrict__ xs) {
    int i = blockIdx.x;
    int b = i >> 7;
    int r = b * NPG + sel[i];
    const f32x4* srcp = (const f32x4*)(x + (size_t)r * DD);
    const f32x4* aggp = (const f32x4*)(agg + (size_t)r * DD);
    f32x4 v = srcp[threadIdx.x];
    f32x4 a = aggp[threadIdx.x];
    #pragma unroll
    for (int j = 0; j < 4; ++j) v[j] += a[j];
    ((f32x4*)(xs + (size_t)i * DD))[threadIdx.x] = v;
}

extern "C" void kernel_launch(void* const* d_in, const int* in_sizes, int n_in,
                              void* d_out, int out_size, void* d_ws, size_t ws_size,
                              hipStream_t stream) {
    const float* x_in = (const float*)d_in[0];
    const int* ei = (const int*)d_in[1];
    const int* sel = (const int*)d_in[2];
    const float* W1 = (const float*)d_in[4];
    const float* b1 = (const float*)d_in[5];
    const float* W2 = (const float*)d_in[6];
    const float* b2 = (const float*)d_in[7];
    const float* g1 = (const float*)d_in[8];
    const float* be1 = (const float*)d_in[9];
    const float* g2 = (const float*)d_in[10];
    const float* be2 = (const float*)d_in[11];
    const float* fW1 = (const float*)d_in[12];
    const float* fb1 = (const float*)d_in[13];
    const float* fW2 = (const float*)d_in[14];
    const float* fb2 = (const float*)d_in[15];
    float* out = (float*)d_out;

    char* w = (char*)d_ws;
    size_t off = 0;
    auto alloc = [&](size_t bytes) -> char* {
        char* p = w + off;
        off += (bytes + 255) & ~(size_t)255;
        return p;
    };
    float* xbuf = (float*)alloc((size_t)NN * DD * 4);
    float* agg  = (float*)alloc((size_t)NN * DD * 4);
    u16* h      = (u16*)alloc((size_t)NN * DD * 2);
    u16* P      = (u16*)alloc((size_t)NN * 1024 * 2);
    u16* W1T    = (u16*)alloc((size_t)LL * 1024 * DD * 2);
    u8* W28T    = (u8*)alloc((size_t)LL * DD * DD);
    u16* FW1T   = (u16*)alloc((size_t)DD * DD * 2);
    u16* FW2T   = (u16*)alloc((size_t)DD * DD * 2);
    int* cnt    = (int*)alloc((size_t)NN * 4);
    int* offs   = (int*)alloc((size_t)(NN + 1) * 4);
    int* cur    = (int*)alloc((size_t)NN * 4);
    int* ssrc   = (int*)alloc((size_t)EE * 4);
    int* sdst   = (int*)alloc((size_t)EE * 4);
    float* xs   = (float*)alloc((size_t)BBATCH * SSEL * DD * 4);
    u16* hs     = (u16*)alloc((size_t)BBATCH * SSEL * DD * 2);
    u16* uu     = (u16*)alloc((size_t)BBATCH * SSEL * DD * 2);

    const int* esrc = ei;       // edge_index[0] = x_j
    const int* edst = ei + EE;  // edge_index[1] = x_i / aggregation index

    (void)hipMemsetAsync(cnt, 0, (size_t)NN * 4, stream);
    hist_kernel<<<EE / 256, 256, 0, stream>>>(edst, cnt);
    scan_kernel<<<1, 1024, 0, stream>>>(cnt, offs, cur);
    scatter_kernel<<<EE / 256, 256, 0, stream>>>(esrc, edst, cur, ssrc, sdst);

    // weight conversions
    cvt_w1_kernel<<<dim3(16, 32, LL), 256, 0, stream>>>(W1, W1T);
    cvt_w28_kernel<<<dim3(16, 16, LL), 256, 0, stream>>>(W2, W28T);
    {
        CvtJobs jobs;
        jobs.s[0] = fW1;
        jobs.s[1] = fW2;
        jobs.d[0] = FW1T;
        jobs.d[1] = FW2T;
        cvt_t2_kernel<<<dim3(16, 16, 2), 256, 0, stream>>>(jobs);
    }

    for (int l = 0; l < LL; ++l) {
        // x_l = x_{l-1} + agg ; h = LN(x_l) ; agg <- 0 for this layer's atomics
        ln_fused<<<NN / 4, 256, 0, stream>>>(l == 0 ? x_in : xbuf, agg, xbuf, g1, be1,
                                             h, l > 0 ? 1 : 0);
        // P = h @ [W1a-W1b | W1b] + [b1 | 0]   [8192 x 1024] bf16
        {
            dim3 grid(NN / 128, 1024 / 128);
            gemm_async<3><<<grid, 256, 0, stream>>>(
                h, W1T + (size_t)l * 1024 * DD, b1 + (size_t)l * DD, nullptr, P, DD,
                1024);
        }
        // fused: edge-combine(fp8, once per edge) + fp8 GEMM2 + segmax atomics
        gemm_edge<<<EE / 64, 512, 0, stream>>>(
            P, ssrc, sdst, W28T + (size_t)l * DD * DD, b2 + (size_t)l * DD, agg);
    }

    gather_fused<<<BBATCH * SSEL, 128, 0, stream>>>(xbuf, agg, sel, xs);
    ln_fused<<<BBATCH * SSEL / 4, 256, 0, stream>>>(xs, nullptr, xs, g2, be2, hs, 0);
    dim3 gridf(BBATCH * SSEL / 128, DD / 128);
    gemm_async<0><<<gridf, 256, 0, stream>>>(hs, FW1T, fb1, nullptr, uu, DD, DD);
    gemm_async<1><<<gridf, 256, 0, stream>>>(uu, FW2T, fb2, xs, out, DD, DD);
}